// Round 1
// baseline (111.659 us; speedup 1.0000x reference)
//
#include <hip/hip_runtime.h>

// WaveletFilterNet fused: haar_forward -> per-channel filter -> haar_inverse
// x: (16,1,2048,2048) fp32, filt: (1,3,1024,1024) fp32, out: (16,1,2048,2048) fp32
//
// Per 2x2 input block {A=x[2i,2j], B=x[2i,2j+1], C=x[2i+1,2j], D=x[2i+1,2j+1]}:
//   P=A+B+C+D (2*LL), Q=A-B-C+D (2*HH), R=A+B-C-D (2*HL), S=A-B+C-D (2*LH)
// Reference's _haar_forward returns (LL, HH, HL, LH), so filt ch0 scales HH,
// ch1 scales HL, ch2 scales LH. Output block:
//   out[2i  ,2j]=.25(P+s0Q+s1R+s2S)  out[2i  ,2j+1]=.25(P-s0Q+s1R-s2S)
//   out[2i+1,2j]=.25(P+s0Q-s1R-s2S)  out[2i+1,2j+1]=.25(P-s0Q-s1R+s2S)

#define B_    16
#define H_    2048
#define W_    2048
#define H2_   1024
#define W2_   1024

__global__ __launch_bounds__(256) void wavelet_fused_kernel(
    const float* __restrict__ x,
    const float* __restrict__ filt,
    float* __restrict__ out)
{
    // One thread handles 2 adjacent 2x2 blocks: a float4 span of 2 rows.
    // total threads = B_ * H2_ * (W2_/2) = 16 * 1024 * 512 = 8,388,608
    const unsigned t = blockIdx.x * blockDim.x + threadIdx.x;

    const unsigned b  = t >> 19;            // / (1024*512)
    const unsigned r  = t & ((1u << 19) - 1u);
    const unsigned i  = r >> 9;             // block row in [0,1024)
    const unsigned jt = r & 511u;           // float4 index in row
    const unsigned j0 = jt << 1;            // block col (2 blocks per thread)

    const long long inOff = (((long long)b * H_) + 2 * i) * W_ + (jt << 2);

    const float4 top = *reinterpret_cast<const float4*>(x + inOff);
    const float4 bot = *reinterpret_cast<const float4*>(x + inOff + W_);

    const long long fOff = (long long)i * W2_ + j0;
    const float2 s0 = *reinterpret_cast<const float2*>(filt + 0 * (H2_ * W2_) + fOff); // scales HH
    const float2 s1 = *reinterpret_cast<const float2*>(filt + 1 * (H2_ * W2_) + fOff); // scales HL
    const float2 s2 = *reinterpret_cast<const float2*>(filt + 2 * (H2_ * W2_) + fOff); // scales LH

    float4 orow0, orow1;
    {   // block 0: A=top.x B=top.y C=bot.x D=bot.y
        const float A = top.x, Bv = top.y, C = bot.x, D = bot.y;
        const float P = A + Bv + C + D;
        const float q = s0.x * (A - Bv - C + D);   // s0*Q (HH)
        const float rr = s1.x * (A + Bv - C - D);  // s1*R (HL)
        const float ss = s2.x * (A - Bv + C - D);  // s2*S (LH)
        orow0.x = 0.25f * (P + q + rr + ss);
        orow0.y = 0.25f * (P - q + rr - ss);
        orow1.x = 0.25f * (P + q - rr - ss);
        orow1.y = 0.25f * (P - q - rr + ss);
    }
    {   // block 1: A=top.z B=top.w C=bot.z D=bot.w
        const float A = top.z, Bv = top.w, C = bot.z, D = bot.w;
        const float P = A + Bv + C + D;
        const float q = s0.y * (A - Bv - C + D);
        const float rr = s1.y * (A + Bv - C - D);
        const float ss = s2.y * (A - Bv + C - D);
        orow0.z = 0.25f * (P + q + rr + ss);
        orow0.w = 0.25f * (P - q + rr - ss);
        orow1.z = 0.25f * (P + q - rr - ss);
        orow1.w = 0.25f * (P - q - rr + ss);
    }

    *reinterpret_cast<float4*>(out + inOff) = orow0;
    *reinterpret_cast<float4*>(out + inOff + W_) = orow1;
}

extern "C" void kernel_launch(void* const* d_in, const int* in_sizes, int n_in,
                              void* d_out, int out_size, void* d_ws, size_t ws_size,
                              hipStream_t stream) {
    const float* x    = (const float*)d_in[0];
    const float* filt = (const float*)d_in[1];
    float* out        = (float*)d_out;

    const unsigned total_threads = B_ * H2_ * (W2_ / 2); // 8,388,608
    const unsigned block = 256;
    const unsigned grid = total_threads / block;         // 32768
    wavelet_fused_kernel<<<grid, block, 0, stream>>>(x, filt, out);
}